// Round 4
// baseline (1081.537 us; speedup 1.0000x reference)
//
#include <hip/hip_runtime.h>

// JointBilateralFilter B=16,C=1,H=768,W=1024 fp32, 9x9, sigma_s=2, sigma_r=0.1.
// valid = (sparse != 1.0); constant pad 1.0 => out-of-image taps never contribute.
// ~5% valid density.
//
// R10 post-mortem: +15% instructions -> +14% time => VALU-ISSUE-THROUGHPUT bound.
// R11: BLOCK-SCATTER. Gather broadcast each entry against the whole 128-px wave
// tile (21% useful slots; 19.2 entries/wave = 0.05*24x16 window). Scatter
// processes each entry ONCE per 32x16-tile block (12 entries/wave = 0.05*40x24/4)
// against its own 9x9 box => 1.6x fewer exp/pk instructions. Contributions land
// in LDS num/den planes covering tile+/-8 (apron discarded => no clip tests, no
// cross-block traffic) via native ds_add_f32 (inline asm; R6's 20x CAS was the
// compiler lowering of generic atomicAdd, not HW). Invalid box lanes (idx>80)
// exec-branched off the adds (else 23-way same-address atomic serialize).
// Acc/depth grid 32 rows x 48 cols, row stride 52 (52 mod 32 = 20 => ~2-way
// banks on scatter). LDS 19968 B => 8 blocks/CU (threads-bound, unchanged).

#define HH 768
#define WW 1024
#define BB 16
#define CS (-0.18033688011112042f)   /* -log2(e)/8  */
#define CR (-72.13475204444817f)     /* -50*log2(e) */

#define GS 52                        /* grid row stride (floats) */
#define PLANE_W (32 * GS)            /* 1664 floats per plane */
#define NUM_OFF_W (PLANE_W)          /* num plane float offset  */
#define DEN_OFF_W (2 * PLANE_W)      /* den plane float offset  */
#define LDS_W (3 * PLANE_W)          /* 4992 floats = 19968 B   */
/* byte offsets for ds_add immediates: num=+6656, den=+13312 */

typedef float f2 __attribute__((ext_vector_type(2)));

__device__ __forceinline__ float rlanef(float v, int b) {
    return __int_as_float(__builtin_amdgcn_readlane(__float_as_int(v), b));
}
__device__ __forceinline__ f2 splat(float x) { f2 r; r.x = x; r.y = x; return r; }

__global__ __launch_bounds__(256) void jbf_kernel(
    const float* __restrict__ sparse,
    const float* __restrict__ depth,
    float* __restrict__ out)
{
    __shared__ __align__(16) float Lds[LDS_W];
    const int tid  = (int)threadIdx.x;
    const int lane = tid & 63;
    const int wv   = tid >> 6;                 // 4 waves/block
    const int TX = (int)blockIdx.x << 5;       // 32-wide tile
    const int TY = (int)blockIdx.y << 4;       // 16-tall tile
    const size_t plane = (size_t)blockIdx.z * (size_t)(HH * WW);
    const float* sp = sparse + plane;
    const float* dp = depth  + plane;

    // ---- Phase A1: zero num+den planes (3328 floats = 832 float4) ----
    {
        float4 z; z.x = 0.f; z.y = 0.f; z.z = 0.f; z.w = 0.f;
        float4* t4 = (float4*)(Lds + NUM_OFF_W);
        #pragma unroll
        for (int i = 0; i < 4; ++i) {
            const int idx = tid + 256 * i;
            if (idx < 832) t4[idx] = z;
        }
    }
    // ---- Phase A2: stage depth 32 rows x 48 cols at origin (TY-8, TX-8), clamped ----
    {
        const int row = tid >> 3;              // 0..31
        const int c0  = (tid & 7) * 6;         // 0,6,...,42
        const int gy  = min(max(TY - 8 + row, 0), HH - 1);
        const float* rowp = dp + (size_t)gy * WW;
        const int gxb = TX - 8 + c0;
        #pragma unroll
        for (int u = 0; u < 3; ++u) {
            const int gx = min(max(gxb + 2 * u, 0), WW - 2);   // even => 8B aligned
            *(f2*)(Lds + row * GS + c0 + 2 * u) = *(const f2*)(rowp + gx);
        }
    }
    __syncthreads();

    // ---- Phase B: scan window strip + scatter ----
    // wave wv scans window rows [6wv, 6wv+6) of the 24x40 window (origin TY-4, TX-4).
    // slot0: iw = lane; slot1: iw = lane+64 (valid iw<120). iw -> (r=iw/20, c2=iw%20).
    const int iw0 = lane, iw1 = lane + 64;
    const int q0 = (iw0 * 3277) >> 16;  const int c20 = iw0 - 20 * q0;
    const int q1 = (iw1 * 3277) >> 16;  const int c21 = iw1 - 20 * q1;
    const int sy0 = TY - 4 + 6 * wv + q0;
    const int sy1 = TY - 4 + 6 * wv + q1;
    const int sx0 = TX - 4 + 2 * c20;
    const int sx1 = TX - 4 + 2 * c21;

    f2 s0, d0, s1, d1;
    {
        const int cy = min(max(sy0, 0), HH - 1), cx = min(max(sx0, 0), WW - 2);
        const size_t o = (size_t)cy * WW + cx;
        s0 = *(const f2*)(sp + o);
        d0 = *(const f2*)(dp + o);
        const bool rok = (unsigned)sy0 < (unsigned)HH;
        if (!(rok && (unsigned)sx0 < (unsigned)WW))       s0.x = 1.0f;
        if (!(rok && (unsigned)(sx0 + 1) < (unsigned)WW)) s0.y = 1.0f;
    }
    {
        const int cy = min(max(sy1, 0), HH - 1), cx = min(max(sx1, 0), WW - 2);
        const size_t o = (size_t)cy * WW + cx;
        s1 = *(const f2*)(sp + o);
        d1 = *(const f2*)(dp + o);
        const bool rok = ((unsigned)sy1 < (unsigned)HH) && (iw1 < 120);
        if (!(rok && (unsigned)sx1 < (unsigned)WW))       s1.x = 1.0f;
        if (!(rok && (unsigned)(sx1 + 1) < (unsigned)WW)) s1.y = 1.0f;
    }

    unsigned long long m00 = __ballot(s0.x != 1.0f);
    unsigned long long m01 = __ballot(s0.y != 1.0f);
    unsigned long long m10 = __ballot(s1.x != 1.0f);
    unsigned long long m11 = __ballot(s1.y != 1.0f);

    // per-lane box-slot constants: box idx ib = 2*lane (+1); (by,bx) = (ib/9, ib%9)
    const int ib0 = 2 * lane, ib1 = 2 * lane + 1;
    const int by0 = (ib0 * 57) >> 9, bx0 = ib0 - 9 * by0;
    const int by1 = (ib1 * 57) >> 9, bx1 = ib1 - 9 * by1;
    const bool v0 = (ib0 <= 80), v1 = (ib1 <= 80);
    const int loff0 = v0 ? (by0 - 4) * GS + (bx0 - 4) : 0;
    const int loff1 = v1 ? (by1 - 4) * GS + (bx1 - 4) : 0;
    f2 tpc;
    tpc.x = v0 ? CS * (float)((by0 - 4) * (by0 - 4) + (bx0 - 4) * (bx0 - 4)) : -1e30f;
    tpc.y = v1 ? CS * (float)((by1 - 4) * (by1 - 4) + (bx1 - 4) * (bx1 - 4)) : -1e30f;
    const f2 crp = splat(CR);
    const int er_base = 6 * wv + 4;            // window row -> acc row (+4)

#define PROCESS(mask, sreg, dreg, base, comp)                                     \
    while (mask) {                                                                \
        const int b = (int)__builtin_ctzll(mask); mask &= (mask - 1ull);          \
        const float sv = rlanef(sreg, b);                                         \
        const float dv = rlanef(dreg, b);                                         \
        const int idx = b + (base);                                               \
        const int qq  = (idx * 3277) >> 16;                                       \
        const int cc2 = idx - 20 * qq;                                            \
        const int er  = qq + er_base;                                             \
        const int ec  = 2 * cc2 + (comp) + 4;                                     \
        const int sbw = er * GS + ec;              /* SALU */                     \
        const int i0 = sbw + loff0;                                               \
        const int i1 = sbw + loff1;                                               \
        f2 myd; myd.x = Lds[i0]; myd.y = Lds[i1];                                 \
        const unsigned va0 = (unsigned)(unsigned long long)&Lds[i0];              \
        const unsigned va1 = (unsigned)(unsigned long long)&Lds[i1];              \
        const f2 diff = splat(dv) - myd;                                          \
        const f2 q    = diff * crp;                                               \
        const f2 arg  = q * diff + tpc;                                           \
        f2 w; w.x = __builtin_amdgcn_exp2f(arg.x);                                \
        w.y = __builtin_amdgcn_exp2f(arg.y);                                      \
        const f2 wsv = w * splat(sv);                                             \
        if (v0) {                                                                 \
            asm volatile("ds_add_f32 %0, %1 offset:6656"  :: "v"(va0), "v"(wsv.x)); \
            asm volatile("ds_add_f32 %0, %1 offset:13312" :: "v"(va0), "v"(w.x));   \
        }                                                                         \
        if (v1) {                                                                 \
            asm volatile("ds_add_f32 %0, %1 offset:6656"  :: "v"(va1), "v"(wsv.y)); \
            asm volatile("ds_add_f32 %0, %1 offset:13312" :: "v"(va1), "v"(w.y));   \
        }                                                                         \
    }

    PROCESS(m00, s0.x, d0.x, 0,  0)
    PROCESS(m01, s0.y, d0.y, 0,  1)
    PROCESS(m10, s1.x, d1.x, 64, 0)
    PROCESS(m11, s1.y, d1.y, 64, 1)
#undef PROCESS

    __syncthreads();

    // ---- Phase C: finalize 512 tile px (2 per thread) ----
    #pragma unroll
    for (int k = 0; k < 2; ++k) {
        const int px  = tid + 256 * k;
        const int row = px >> 5, col = px & 31;
        const int ai  = (row + 8) * GS + (col + 8);
        const float nu = Lds[NUM_OFF_W + ai];
        const float de = Lds[DEN_OFF_W + ai];
        float r = nu * __builtin_amdgcn_rcpf(de + 1e-8f);
        r = (de < 1e-8f) ? 1.0f : r;
        out[plane + (size_t)(TY + row) * WW + (TX + col)] = r;
    }
}

extern "C" void kernel_launch(void* const* d_in, const int* in_sizes, int n_in,
                              void* d_out, int out_size, void* d_ws, size_t ws_size,
                              hipStream_t stream)
{
    const float* sparse = (const float*)d_in[0];
    const float* depth  = (const float*)d_in[1];
    float* out = (float*)d_out;
    dim3 grid(WW / 32, HH / 16, BB);   // 32 x 48 x 16 blocks, 256 threads
    jbf_kernel<<<grid, dim3(256, 1, 1), 0, stream>>>(sparse, depth, out);
}

// Round 5
// 175.477 us; speedup vs baseline: 6.1634x; 6.1634x over previous
//
#include <hip/hip_runtime.h>

// JointBilateralFilter B=16,C=1,H=768,W=1024 fp32, 9x9, sigma_s=2, sigma_r=0.1.
// valid = (sparse != 1.0); constant pad 1.0 => out-of-image taps never contribute.
// ~5% valid density.
//
// Structure: R9 pixel-packed gather-scan (wave tile 16x8, 2 px/lane, packed f2
// math, LDS sentinel table, uniform ballot loop). R10 (loads-first reorder):
// +15% instr -> +14% time => VALU-ISSUE bound, reverted. R11 (LDS ds_add_f32
// scatter): 12x regression, VALUBusy 6% => DS atomic throughput wall, dead.
//
// R12 (this round): AMORTIZE PER-WAVE FIXED COST (~60 of 84 us by R10's
// marginal coefficient: loop is only ~25 us). Each block processes FOUR 32-wide
// tiles along x: (1) constant spatial table built once instead of 4x, (2) wave
// setup hoisted, (3) tile t+1's staging loads issue BEFORE tile t's entry loop
// (double-buffered A/B register sets, no dynamic indexing) so ~900cy HBM
// latency hides under ~600cy of loop compute (T14 async-stage pattern).

#define HH 768
#define WW 1024
#define BB 16
#define CS (-0.18033688011112042f)   /* -log2(e)/8  */
#define CR (-72.13475204444817f)     /* -50*log2(e) */

#define TS 68                        /* table row stride: 2-way-per-half banks (free) */
#define TROWS 31                     /* dy in [-15,15] */
#define TSIZE (TROWS * TS)           /* 2108 floats = 8432 B */
#define TF4   (TSIZE / 4)            /* 527 float4 */

typedef float f2 __attribute__((ext_vector_type(2)));

__device__ __forceinline__ int rfl(int x) { return __builtin_amdgcn_readfirstlane(x); }
__device__ __forceinline__ float rlanef(float v, int b) {
    return __int_as_float(__builtin_amdgcn_readlane(__float_as_int(v), b));
}
__device__ __forceinline__ f2 splat(float x) { f2 r; r.x = x; r.y = x; return r; }

__global__ __launch_bounds__(256) void jbf_kernel(
    const float* __restrict__ sparse,
    const float* __restrict__ depth,
    float* __restrict__ out)
{
    __shared__ __align__(16) float Tab[TSIZE];
    const int tid  = (int)threadIdx.x;
    const int lane = tid & 63;
    const int wv   = tid >> 6;                    // 4 waves/block, 2x2 tiles

    // ---- table build (ONCE per block, shared by all 4 tiles) ----
    {
        float4 s; s.x = -1e30f; s.y = -1e30f; s.z = -1e30f; s.w = -1e30f;
        float4* t4 = (float4*)Tab;
        #pragma unroll
        for (int i = 0; i < 3; ++i) {
            const int idx = tid + 256 * i;
            if (idx < TF4) t4[idx] = s;
        }
    }
    __syncthreads();
    if (tid < 81) {
        const int rr = (tid * 57) >> 9;           // tid/9 for tid<81
        const int cc = tid - 9 * rr;
        const float dy = (float)(rr - 4), dx = (float)(cc - 4);
        Tab[(rr + 11) * TS + cc + 19] = CS * fmaf(dy, dy, dx * dx);
    }
    __syncthreads();

    // ---- hoisted wave-uniform constants ----
    const int ty  = rfl(((int)blockIdx.y << 4) + ((wv >> 1) << 3));  // 8-tall tile
    const int py0 = rfl(min(max(ty - 4, 0), HH - 16));               // 16-row window
    const int tyoff = ty - py0;                   // 0..8
    const int sbrow = TS * (15 - tyoff);          // row part of sbase0

    const size_t plane = (size_t)blockIdx.z * (size_t)(HH * WW);
    const float* sp = sparse + plane;
    const float* dp = depth  + plane;

    const int r  = lane >> 2;                     // 0..15 window row
    const int c0 = (lane & 3) << 1;               // float2 col 0,2,4,6 (+8 per j)
    const int my = lane >> 3, mx = lane & 7;
    const int gy = ty + my;
    const int clane_w = my * TS + mx;             // per-lane table float offset
    const f2 crp = splat(CR);

    // block covers 128 px in x: 4 tiles of 32 (2 waves each 16 wide)
    const int txb = rfl((int)blockIdx.x * 128 + ((wv & 1) << 4));

// ---- staging: assign into pre-declared register set ----
#define STAGE(TX, PX0, S0, S1, S2, D0, D1, D2, M0, M1)                    \
    const int PX0 = rfl(min(max((TX) - 4, 0), WW - 24));                  \
    {                                                                      \
        const float* wbs = sp + (size_t)(py0 + r) * WW + PX0 + c0;        \
        const float* wbd = dp + (size_t)(py0 + r) * WW + PX0 + c0;        \
        S0 = *(const f2*)(wbs);                                            \
        S1 = *(const f2*)(wbs + 8);                                        \
        S2 = *(const f2*)(wbs + 16);                                       \
        D0 = *(const f2*)(wbd);                                            \
        D1 = *(const f2*)(wbd + 8);                                        \
        D2 = *(const f2*)(wbd + 16);                                       \
        M0 = dp[(size_t)gy * WW + (TX) + mx];                              \
        M1 = dp[(size_t)gy * WW + (TX) + mx + 8];                          \
    }

// ---- process one 16x8 wave tile (R9 inner loop verbatim) ----
#define PROCESS(TX, PX0, S0, S1, S2, D0, D1, D2, M0, M1)                  \
    {                                                                      \
        const int txoff = (TX) - PX0;             /* 0..8 */               \
        const int sbase0 = sbrow + (23 - txoff) - 8;                       \
        f2 nmyd; nmyd.x = -(M0); nmyd.y = -(M1);                           \
        f2 numA = splat(0.0f), denA = splat(0.0f);                         \
        f2 numB = splat(0.0f), denB = splat(0.0f);                         \
        _Pragma("unroll")                                                  \
        for (int j = 0; j < 3; ++j) {                                      \
            const f2 s2 = (j == 0) ? S0 : (j == 1) ? S1 : S2;              \
            const f2 d2 = (j == 0) ? D0 : (j == 1) ? D1 : D2;              \
            _Pragma("unroll")                                              \
            for (int k = 0; k < 2; ++k) {                                  \
                const float svk = k ? s2.y : s2.x;                         \
                const float dvk = k ? d2.y : d2.x;                         \
                const int sbase = sbase0 + 8 * j + k;      /* SALU */      \
                unsigned long long m = __ballot(svk != 1.0f);              \
                while (m) {                                /* uniform */   \
                    const int b0 = (int)__builtin_ctzll(m);                \
                    m &= (m - 1ull);                                       \
                    {                                                      \
                        const float sv_e = rlanef(svk, b0);                \
                        const float dv_e = rlanef(dvk, b0);                \
                        const int SW = sbase + (b0 >> 2) * TS              \
                                       + ((b0 & 3) << 1);  /* SALU */      \
                        const float* tb = Tab + (SW - clane_w);            \
                        f2 tp; tp.x = tb[8]; tp.y = tb[0]; /* ds_read2 */  \
                        const f2 diff = nmyd + splat(dv_e);                \
                        const f2 q = diff * crp;                           \
                        const f2 arg = q * diff + tp;      /* pk_fma */    \
                        f2 w; w.x = __builtin_amdgcn_exp2f(arg.x);         \
                        w.y = __builtin_amdgcn_exp2f(arg.y);               \
                        denA += w;                                         \
                        numA += w * splat(sv_e);           /* pk_fma */    \
                    }                                                      \
                    if (m) {                               /* B chain */   \
                        const int b1 = (int)__builtin_ctzll(m);            \
                        m &= (m - 1ull);                                   \
                        const float sv_e = rlanef(svk, b1);                \
                        const float dv_e = rlanef(dvk, b1);                \
                        const int SW = sbase + (b1 >> 2) * TS              \
                                       + ((b1 & 3) << 1);                  \
                        const float* tb = Tab + (SW - clane_w);            \
                        f2 tp; tp.x = tb[8]; tp.y = tb[0];                 \
                        const f2 diff = nmyd + splat(dv_e);                \
                        const f2 q = diff * crp;                           \
                        const f2 arg = q * diff + tp;                      \
                        f2 w; w.x = __builtin_amdgcn_exp2f(arg.x);         \
                        w.y = __builtin_amdgcn_exp2f(arg.y);               \
                        denB += w;                                         \
                        numB += w * splat(sv_e);                           \
                    }                                                      \
                }                                                          \
            }                                                              \
        }                                                                  \
        const float n0 = numA.x + numB.x, n1 = numA.y + numB.y;            \
        const float e0 = denA.x + denB.x, e1 = denA.y + denB.y;            \
        float r0 = n0 * __builtin_amdgcn_rcpf(e0 + 1e-8f);                 \
        r0 = (e0 < 1e-8f) ? 1.0f : r0;                                     \
        float r1 = n1 * __builtin_amdgcn_rcpf(e1 + 1e-8f);                 \
        r1 = (e1 < 1e-8f) ? 1.0f : r1;                                     \
        float* op = out + plane + (size_t)gy * WW + (TX) + mx;             \
        op[0] = r0;                                                        \
        op[8] = r1;                                                        \
    }

    // ---- two register sets, 1-ahead software pipeline over 4 tiles ----
    f2 sA0, sA1, sA2, dA0, dA1, dA2; float mA0, mA1;
    f2 sB0, sB1, sB2, dB0, dB1, dB2; float mB0, mB1;

    const int tx0 = txb;
    const int tx1 = txb + 32;
    const int tx2 = txb + 64;
    const int tx3 = txb + 96;

    STAGE(tx0, px0a, sA0, sA1, sA2, dA0, dA1, dA2, mA0, mA1)   // tile 0 loads
    STAGE(tx1, px0b, sB0, sB1, sB2, dB0, dB1, dB2, mB0, mB1)   // tile 1 loads (in flight)
    PROCESS(tx0, px0a, sA0, sA1, sA2, dA0, dA1, dA2, mA0, mA1) // compute tile 0
    STAGE(tx2, px0c, sA0, sA1, sA2, dA0, dA1, dA2, mA0, mA1)   // tile 2 loads (in flight)
    PROCESS(tx1, px0b, sB0, sB1, sB2, dB0, dB1, dB2, mB0, mB1) // compute tile 1
    STAGE(tx3, px0d, sB0, sB1, sB2, dB0, dB1, dB2, mB0, mB1)   // tile 3 loads (in flight)
    PROCESS(tx2, px0c, sA0, sA1, sA2, dA0, dA1, dA2, mA0, mA1) // compute tile 2
    PROCESS(tx3, px0d, sB0, sB1, sB2, dB0, dB1, dB2, mB0, mB1) // compute tile 3

#undef STAGE
#undef PROCESS
}

extern "C" void kernel_launch(void* const* d_in, const int* in_sizes, int n_in,
                              void* d_out, int out_size, void* d_ws, size_t ws_size,
                              hipStream_t stream)
{
    const float* sparse = (const float*)d_in[0];
    const float* depth  = (const float*)d_in[1];
    float* out = (float*)d_out;
    dim3 grid(WW / 128, HH / 16, BB);   // 8 x 48 x 16 blocks, 4 waves, 4 tiles/block
    jbf_kernel<<<grid, dim3(256, 1, 1), 0, stream>>>(sparse, depth, out);
}